// Round 8
// baseline (201.462 us; speedup 1.0000x reference)
//
#include <hip/hip_runtime.h>

// B=2, S=2048, D=1024, H=16, DH=64.
// 3 launches:
//  convert_all : fused W transpose->bf16 and q/k/v fp32->bf16.
//  proj_gemm   : z=3, Outh[w] = Xb @ Wt^T + bias. which==0 pre-scaled by
//                log2e/32 (exp2-domain softmax); which==2 stored transposed.
//                Bijective XCD-chunked swizzle (768=8x96).
//  attn_kernel : flash attention, FIXED-max exp2 softmax, in-register P.
//                R8: 256-q blocks, 8 waves, 1 block/CU (2 w/SIMD, R7's
//                proven TLP point). Wave pair owns 64 q; each wave does ONE
//                64-key sub-tile (parity w&1) with qs=4: K/V fragment
//                ds_reads HALVE per CU (amortized over 4 q-strips) and ILP
//                doubles to 4 chains. Parity epilogue-combine from R6.
//                launch_bounds(512,1): 256-VGPR cap (qs=4 needs ~220;
//                (512,2) would cap 128 and spill -- R4 lesson).

#define B_ 2
#define S_ 2048
#define D_ 1024
#define H_ 16
#define DH_ 64
#define M_ (B_*S_)   // 4096

#define WT_OFF  ((size_t)3*4194304)            // u16 offset of Wt
#define XB_OFF  (WT_OFF + (size_t)3*1048576)   // u16 offset of Xb slot (q)

typedef __attribute__((ext_vector_type(8))) short short8;
typedef __attribute__((ext_vector_type(4))) float f32x4;
typedef __attribute__((ext_vector_type(4))) unsigned int u32x4;
#define MFMA16(a,b,c) __builtin_amdgcn_mfma_f32_16x16x32_bf16(a,b,c,0,0,0)

typedef __attribute__((address_space(1))) const void* gptr_t;
typedef __attribute__((address_space(3))) void* lptr_t;
static __device__ inline void gload_lds16(const void* g, void* l) {
    __builtin_amdgcn_global_load_lds((gptr_t)g, (lptr_t)l, 16, 0, 0);
}

static __device__ inline unsigned short f2bf(float x) {   // RNE
    union { float f; unsigned u; } v; v.f = x;
    return (unsigned short)((v.u + 0x7fffu + ((v.u >> 16) & 1u)) >> 16);
}
// pack two floats to bf16 pair (round-half-up): 2 adds + 1 v_perm_b32
static __device__ inline unsigned packp(float a, float b) {
    return __builtin_amdgcn_perm(__float_as_uint(b) + 0x8000u,
                                 __float_as_uint(a) + 0x8000u, 0x07060302u);
}

// ---------------------------------------------------------------------------
// Fused conversions. Grid (4096+256, 1, 3).
//   bx <  4096 : X (q/k/v) fp32 -> bf16, 1024 elems/block
//   bx >= 4096 : W fp32 [k][n] -> bf16 Wt [n][k], 64x64 tile via LDS
// ---------------------------------------------------------------------------
__global__ __launch_bounds__(256) void convert_all(
    const float* __restrict__ X0, const float* __restrict__ X1,
    const float* __restrict__ X2,
    const float* __restrict__ Wq, const float* __restrict__ Wk,
    const float* __restrict__ Wv,
    unsigned short* __restrict__ O0, unsigned short* __restrict__ O1,
    unsigned short* __restrict__ O2, unsigned short* __restrict__ WtBase)
{
    __shared__ unsigned short T[64][72];
    const int z = blockIdx.z;
    const int t = threadIdx.x;

    if (blockIdx.x < 4096) {
        const float* X = z==0 ? X0 : (z==1 ? X1 : X2);
        unsigned short* O = z==0 ? O0 : (z==1 ? O1 : O2);
        int idx = blockIdx.x*256 + t;
        float4 xv = *(const float4*)&X[(size_t)idx*4];
        uint2 o;
        o.x = (unsigned)f2bf(xv.x) | ((unsigned)f2bf(xv.y) << 16);
        o.y = (unsigned)f2bf(xv.z) | ((unsigned)f2bf(xv.w) << 16);
        *(uint2*)&O[(size_t)idx*4] = o;
        return;
    }

    const float* W = z==0 ? Wq : (z==1 ? Wk : Wv);
    unsigned short* Out = WtBase + ((size_t)z << 20);
    const int bx2 = blockIdx.x - 4096;
    const int n0 = (bx2 & 15)*64, k0 = (bx2 >> 4)*64;
    const int tk = t >> 4, tn4 = (t & 15)*4;

    #pragma unroll
    for (int i=0;i<4;i++){
        int kk = tk + i*16;
        float4 wv = *(const float4*)&W[(size_t)(k0+kk)*D_ + n0 + tn4];
        T[tn4+0][kk] = f2bf(wv.x);
        T[tn4+1][kk] = f2bf(wv.y);
        T[tn4+2][kk] = f2bf(wv.z);
        T[tn4+3][kk] = f2bf(wv.w);
    }
    __syncthreads();

    const int n = t >> 2, seg = t & 3;
    uint4 a = *(uint4*)&T[n][seg*16];
    uint4 b = *(uint4*)&T[n][seg*16 + 8];
    *(uint4*)&Out[(size_t)(n0+n)*D_ + k0 + seg*16]     = a;
    *(uint4*)&Out[(size_t)(n0+n)*D_ + k0 + seg*16 + 8] = b;
}

// ---------------------------------------------------------------------------
// Projection GEMM, pure-DMA staging, XOR-swizzled LDS. Grid (8,32,3).
// which==0: output scaled by log2e/32.  which==2: output transposed.
// XCD-chunked block swizzle: XCD k handles 12 contiguous (m,z)-panels.
// ---------------------------------------------------------------------------
__global__ __launch_bounds__(256) void proj_gemm(
    const unsigned short* __restrict__ A0, const unsigned short* __restrict__ A1,
    const unsigned short* __restrict__ A2, const unsigned short* __restrict__ WtBase,
    const float* __restrict__ b0, const float* __restrict__ b1,
    const float* __restrict__ b2, unsigned short* __restrict__ OutBase)
{
    // 768 blocks = 8 XCDs x 96. hw lin%8 ~ XCD -> give each XCD a contiguous
    // chunk of (x,y,z) linear space (12 A-panels x 8 B-tiles).
    const int lin0 = blockIdx.x + (blockIdx.y << 3) + (blockIdx.z << 8);
    const int swz  = (lin0 & 7)*96 + (lin0 >> 3);
    const int bxn  = swz & 7;
    const int byn  = (swz >> 3) & 31;
    const int which = swz >> 8;

    const unsigned short* A  = which==0 ? A0 : (which==1 ? A1 : A2);
    const unsigned short* Bm = WtBase + ((size_t)which << 20);
    const float* bias        = which==0 ? b0 : (which==1 ? b1 : b2);
    unsigned short* Out      = OutBase + ((size_t)which << 22);
    const float oscale = (which==0) ? 0.04508422f : 1.0f;   // log2e/32

    __shared__ __align__(16) unsigned short As[128*64];
    __shared__ __align__(16) unsigned short Bs[128*64];

    const int t    = threadIdx.x;
    const int m0   = byn * 128;
    const int n0   = bxn * 128;
    const int w    = t >> 6;
    const int lane = t & 63;
    const int l15  = lane & 15;
    const int quad = lane >> 4;
    const int wm   = w >> 1, wn = w & 1;

    f32x4 acc[4][4];
    #pragma unroll
    for (int i=0;i<4;i++)
        #pragma unroll
        for (int j=0;j<4;j++) acc[i][j] = (f32x4){0.f,0.f,0.f,0.f};

    float biasv[4];
    #pragma unroll
    for (int nt=0; nt<4; nt++)
        biasv[nt] = bias[n0 + wn*64 + nt*16 + l15];

    int sArow[4], sAkc[4];
    #pragma unroll
    for (int i=0;i<4;i++){
        int s  = (w*4 + i)*64 + lane;
        int r  = s >> 3, cs = s & 7;
        sArow[i] = r;
        sAkc[i]  = ((cs ^ (r & 7)) * 8);
    }

    for (int ks = 0; ks < 16; ++ks) {
        const int kb = ks * 64;
        #pragma unroll
        for (int i=0;i<4;i++){
            int s = (w*4 + i)*64 + lane;
            gload_lds16(A  + (size_t)(m0 + sArow[i])*D_ + kb + sAkc[i], (unsigned short*)As + s*8);
            gload_lds16(Bm + (size_t)(n0 + sArow[i])*D_ + kb + sAkc[i], (unsigned short*)Bs + s*8);
        }
        __syncthreads();

        #pragma unroll
        for (int kh=0; kh<2; kh++){
            short8 aF[4], bF[4];
            #pragma unroll
            for (int mt=0; mt<4; mt++){
                int r  = wm*64 + mt*16 + l15;
                int cs = (kh*4 + quad) ^ (r & 7);
                aF[mt] = *(const short8*)(As + r*64 + cs*8);
            }
            #pragma unroll
            for (int nt=0; nt<4; nt++){
                int r  = wn*64 + nt*16 + l15;
                int cs = (kh*4 + quad) ^ (r & 7);
                bF[nt] = *(const short8*)(Bs + r*64 + cs*8);
            }
            #pragma unroll
            for (int mt=0; mt<4; mt++)
                #pragma unroll
                for (int nt=0; nt<4; nt++)
                    acc[mt][nt] = MFMA16(aF[mt], bF[nt], acc[mt][nt]);
        }
        __syncthreads();
    }

    if (which != 2) {
        #pragma unroll
        for (int nt=0; nt<4; nt++){
            int n  = n0 + wn*64 + nt*16 + l15;
            int hh = n >> 6, dh = n & 63;
            #pragma unroll
            for (int mt=0; mt<4; mt++){
                #pragma unroll
                for (int r=0; r<4; r++){
                    int m  = m0 + wm*64 + mt*16 + quad*4 + r;
                    int bb = m >> 11, ss = m & (S_-1);
                    float v = (acc[mt][nt][r] + biasv[nt]) * oscale;
                    Out[((size_t)((bb*H_ + hh)*S_ + ss))*DH_ + dh] = f2bf(v);
                }
            }
        }
    } else {
        #pragma unroll
        for (int nt=0; nt<4; nt++){
            int n  = n0 + wn*64 + nt*16 + l15;
            int hh = n >> 6, dh = n & 63;
            #pragma unroll
            for (int mt=0; mt<4; mt++){
                int m  = m0 + wm*64 + mt*16 + quad*4;
                int bb = m >> 11, ss = m & (S_-1);
                uint2 pk;
                pk.x = packp(acc[mt][nt][0] + biasv[nt], acc[mt][nt][1] + biasv[nt]);
                pk.y = packp(acc[mt][nt][2] + biasv[nt], acc[mt][nt][3] + biasv[nt]);
                *(uint2*)&Out[((size_t)((bb*H_ + hh)*DH_ + dh))*S_ + ss] = pk;
            }
        }
    }
}

// ---------------------------------------------------------------------------
// Flash attention, fixed-max exp2 softmax, in-register P.
// Block = 256 q of one (b,h); 8 waves. Wave pair (2j,2j+1) owns q rows
// j*64..j*64+63; each wave handles ONE 64-key sub-tile (parity pb=w&1)
// with qs=4 (4 independent QK->exp2->pack->PV chains). Grid (8,16,2) =
// 256 blocks = 1 block/CU = 2 waves/SIMD. K/V fragment ds_reads per CU are
// HALF of R7 (each fragment amortized over 4 q-strips). One barrier per
// 128 keys. Parity partials combined in epilogue (fixed-max softmax ->
// merge-free). Static mask-bias table as QK MFMA C-init. XCD-swizzled.
//
// Key-row permutation (per 64-key sub-tile): LDS K row l holds global key
//   g(l) = 32*(st&1) + 8*quad + 4*(st>>1) + r   (l = st*16+quad*4+r)
// so QK^T output sc[st][r] (lane quad) is the score of key 32(st&1)+8q+4(st>>1)+r,
// and {st0,st2} / {st1,st3} pack directly into pf0/pf1 (PV B-frag, k=quad*8+j).
// V^T is stored by TRUE key, matching the B-frag k index.
// ---------------------------------------------------------------------------
__global__ __launch_bounds__(512, 1) void attn_kernel(
    const unsigned short* __restrict__ ws, const int* __restrict__ mask,
    float* __restrict__ out)
{
    const unsigned short* Qh = ws;                      // [B][H][S][64], exp2-scaled
    const unsigned short* Kh = ws + (size_t)M_*D_;      // [B][H][S][64]
    const unsigned short* Vg = ws + 2*(size_t)M_*D_;    // [B][H][64][S]

    // XCD swizzle: XCD x gets 32 consecutive Wn = all 8 q-tiles of 4 heads
    // -> 2 MB K/V working set per XCD L2.
    const int lin = blockIdx.x + (blockIdx.y << 3) + (blockIdx.z << 7);
    const int Wn  = (lin & 7)*32 + (lin >> 3);
    const int qt = Wn & 7;
    const int h  = (Wn >> 3) & 15;
    const int bb = Wn >> 7;

    const size_t base = ((size_t)(bb*H_ + h)) * S_ * DH_;
    const int q0 = qt * 256;

    __shared__ __align__(16) unsigned char smem[73728];
    unsigned short* KsB = (unsigned short*)smem;            // [2][128][64] key-permuted
    unsigned short* VtB = (unsigned short*)(smem + 32768);  // [2][128][64] true-key order
    float*          MsT = (float*)(smem + 65536);           // [2048] static mask bias
    float*          Ob  = (float*)smem;                     // [256][68] f32 alias (epi)
    float*          Lb  = (float*)(smem + 69632);           // [2][256] partial l (epi)
    float*          invL= (float*)(smem + 71680);           // [256] (epi)

    const int t    = threadIdx.x;    // 0..511
    const int w    = t >> 6;         // 0..7
    const int lane = t & 63;
    const int l15  = lane & 15;
    const int quad = lane >> 4;
    const int qw   = w >> 1;         // q-row group (x64)
    const int pb   = w & 1;          // key sub-tile parity

    short8 qf[4][2];
    #pragma unroll
    for (int qs=0; qs<4; qs++){
        const unsigned short* qp = Qh + base + (size_t)(q0 + qw*64 + qs*16 + l15)*DH_ + quad*8;
        qf[qs][0] = *(const short8*)(qp);
        qf[qs][1] = *(const short8*)(qp + 32);
    }

    f32x4 accO[4][4];
    #pragma unroll
    for (int qs=0; qs<4; qs++)
        #pragma unroll
        for (int i=0;i<4;i++) accO[qs][i] = (f32x4){0.f,0.f,0.f,0.f};
    f32x4 lv[4];
    #pragma unroll
    for (int qs=0; qs<4; qs++) lv[qs] = (f32x4){0.f,0.f,0.f,0.f};

    // staging: 8 waves x 2 slots x 64 lanes = 1024 slots of 16B per buffer.
    // slot row r in 0..127: sub-tile = r>>6, within-sub row = r&63.
    int rr[2], cc[2], ssl[2], gK[2];
    #pragma unroll
    for (int i=0;i<2;i++){
        int s  = (w*2 + i)*64 + lane;   // 0..1023
        int r  = s >> 3, cs = s & 7;
        int r6 = r & 63;
        ssl[i] = s;
        rr[i]  = r;
        cc[i]  = (cs ^ (r & 7)) * 8;
        gK[i]  = (r & 64) + ((r6 >> 4) & 1)*32 + ((r6 >> 2) & 3)*8 + (r6 >> 5)*4 + (r6 & 3);
    }

    #define ISSUE128(k0v, p) do {                                              \
        _Pragma("unroll")                                                      \
        for (int i=0;i<2;i++){                                                 \
            gload_lds16(Kh + base + (size_t)((k0v) + gK[i])*DH_ + cc[i],       \
                        KsB + (p)*8192 + ssl[i]*8);                            \
            gload_lds16(Vg + base + (size_t)(rr[i] & 63)*S_ + (k0v)            \
                            + (rr[i] & 64) + cc[i],                            \
                        VtB + (p)*8192 + ssl[i]*8);                            \
        }                                                                      \
    } while(0)

    // prologue: static mask-bias table + first DMA tile
    ISSUE128(0, 0);
    #pragma unroll
    for (int i=0;i<4;i++){
        int idx = i*512 + t;
        MsT[idx] = mask[bb*S_ + idx] ? 0.f : -1e9f;
    }
    __syncthreads();

    for (int it = 0; it < 16; ++it){
        const int p = it & 1;
        if (it < 15) ISSUE128((it+1)*128, 1-p);

        // this wave's sub-tile (parity pb) of the 128-key tile
        const unsigned short* Ks  = KsB + p*8192 + pb*4096;
        const unsigned short* Vts = VtB + p*8192 + pb*4096;
        const float*          Mp  = MsT + it*128 + pb*64;

        // mask bias in permuted-key order (MFMA C-init):
        // key(st,quad,r) = 32(st&1)+4(st>>1)+8quad+r
        f32x4 msv[4];
        #pragma unroll
        for (int st=0; st<4; st++)
            msv[st] = *(const f32x4*)&Mp[(st&1)*32 + (st>>1)*4 + quad*8];

        // K/V fragments: loaded ONCE, shared by all 4 qs chains
        short8 ka[4], kb[4];
        #pragma unroll
        for (int st=0; st<4; st++){
            int row = st*16 + l15;
            const unsigned short* kr = Ks + row*64;
            ka[st] = *(const short8*)(kr + ((quad    ) ^ (row & 7))*8);
            kb[st] = *(const short8*)(kr + ((quad + 4) ^ (row & 7))*8);
        }
        short8 vf[4][2];
        #pragma unroll
        for (int mt=0; mt<4; mt++){
            int row = mt*16 + l15;
            const unsigned short* vr = Vts + row*64;
            vf[mt][0] = *(const short8*)(vr + ((quad    ) ^ (row & 7))*8);
            vf[mt][1] = *(const short8*)(vr + ((quad + 4) ^ (row & 7))*8);
        }

        #pragma unroll
        for (int qs=0; qs<4; qs++){
            // ---- scores: S^T = K·Q^T, mask bias as accumulator init ----
            f32x4 sc[4];
            __builtin_amdgcn_s_setprio(1);
            #pragma unroll
            for (int st=0; st<4; st++){
                f32x4 a = msv[st];
                a = MFMA16(ka[st], qf[qs][0], a);
                a = MFMA16(kb[st], qf[qs][1], a);
                sc[st] = a;
            }
            __builtin_amdgcn_s_setprio(0);
            // ---- fixed-max softmax, tree-summed l, packed into B-frag ----
            f32x4 pvv[4];
            #pragma unroll
            for (int st=0; st<4; st++)
                #pragma unroll
                for (int rj=0; rj<4; rj++)
                    pvv[st][rj] = __builtin_amdgcn_exp2f(sc[st][rj]);
            f32x4 s01 = pvv[0] + pvv[1];
            f32x4 s23 = pvv[2] + pvv[3];
            lv[qs] += (s01 + s23);
            u32x4 u0 = { packp(pvv[0][0],pvv[0][1]), packp(pvv[0][2],pvv[0][3]),
                         packp(pvv[2][0],pvv[2][1]), packp(pvv[2][2],pvv[2][3]) };
            u32x4 u1 = { packp(pvv[1][0],pvv[1][1]), packp(pvv[1][2],pvv[1][3]),
                         packp(pvv[3][0],pvv[3][1]), packp(pvv[3][2],pvv[3][3]) };
            short8 pf0 = __builtin_bit_cast(short8, u0);
            short8 pf1 = __builtin_bit_cast(short8, u1);
            // ---- PV: O^T += V^T · P^T (P entirely in registers) ----
            __builtin_amdgcn_s_setprio(1);
            #pragma unroll
            for (int mt=0; mt<4; mt++){
                accO[qs][mt] = MFMA16(vf[mt][0], pf0, accO[qs][mt]);
                accO[qs][mt] = MFMA16(vf[mt][1], pf1, accO[qs][mt]);
            }
            __builtin_amdgcn_s_setprio(0);
        }
        __syncthreads();
    }

    // ---- epilogue: combine wave-pair partials in LDS, normalize, store ----
    float lpart[4];
    #pragma unroll
    for (int qs=0; qs<4; qs++){
        float l = (lv[qs][0] + lv[qs][1]) + (lv[qs][2] + lv[qs][3]);
        l += __shfl_xor(l, 16);
        l += __shfl_xor(l, 32);
        lpart[qs] = l;
    }
    if (quad == 0){
        #pragma unroll
        for (int qs=0; qs<4; qs++)
            Lb[pb*256 + qw*64 + qs*16 + l15] = lpart[qs];
    }
    if (pb == 0){
        #pragma unroll
        for (int qs=0; qs<4; qs++)
            #pragma unroll
            for (int mt=0; mt<4; mt++)
                #pragma unroll
                for (int r=0; r<4; r++)
                    Ob[(qw*64 + qs*16 + l15)*68 + mt*16 + quad*4 + r] = accO[qs][mt][r];
    }
    __syncthreads();
    if (pb == 1){
        #pragma unroll
        for (int qs=0; qs<4; qs++)
            #pragma unroll
            for (int mt=0; mt<4; mt++)
                #pragma unroll
                for (int r=0; r<4; r++)
                    Ob[(qw*64 + qs*16 + l15)*68 + mt*16 + quad*4 + r] += accO[qs][mt][r];
    }
    if (t < 256) invL[t] = 1.0f / fmaxf(Lb[t] + Lb[256 + t], 1e-30f);
    __syncthreads();

    #pragma unroll
    for (int i=0;i<8;i++){
        int f  = (i*512 + t)*4;
        int qq = f >> 6, dh = f & 63;
        float4 o = *(float4*)&Ob[qq*68 + dh];
        float s = invL[qq];
        o.x *= s; o.y *= s; o.z *= s; o.w *= s;
        *(float4*)&out[((size_t)(bb*S_ + q0 + qq))*D_ + h*DH_ + dh] = o;
    }
    #undef ISSUE128
}

extern "C" void kernel_launch(void* const* d_in, const int* in_sizes, int n_in,
                              void* d_out, int out_size, void* d_ws, size_t ws_size,
                              hipStream_t stream) {
    const float* q    = (const float*)d_in[0];
    const float* k    = (const float*)d_in[1];
    const float* v    = (const float*)d_in[2];
    const int*   mask = (const int*)d_in[3];
    const float* Wq   = (const float*)d_in[4];
    const float* b0   = (const float*)d_in[5];
    const float* Wk   = (const float*)d_in[6];
    const float* b1   = (const float*)d_in[7];
    const float* Wv   = (const float*)d_in[8];
    const float* b2   = (const float*)d_in[9];
    float* out = (float*)d_out;
    unsigned short* ws = (unsigned short*)d_ws;   // 39.85 MB used

    // Xb slots: q -> ws; k,v -> d_out (scratch until attn overwrites it last)
    unsigned short* xq = ws + XB_OFF;
    unsigned short* xk = (unsigned short*)d_out;
    unsigned short* xv = (unsigned short*)d_out + 4194304;

    convert_all<<<dim3(4352,1,3), 256, 0, stream>>>(q, k, v, Wq, Wk, Wv,
                                                    xq, xk, xv, ws + WT_OFF);
    proj_gemm<<<dim3(8,32,3), 256, 0, stream>>>(xq, xk, xv, ws + WT_OFF,
                                                b0, b1, b2, ws);
    attn_kernel<<<dim3(8,16,2), 512, 0, stream>>>(ws, mask, out);
}

// Round 9
// 196.577 us; speedup vs baseline: 1.0248x; 1.0248x over previous
//
#include <hip/hip_runtime.h>

// B=2, S=2048, D=1024, H=16, DH=64.
// 3 launches:
//  convert_all : fused W transpose->bf16 and q/k/v fp32->bf16.
//  proj_gemm   : z=3, Outh[w] = Xb @ Wt^T + bias. which==0 pre-scaled by
//                log2e/32 (exp2-domain softmax); which==2 stored transposed.
//                Bijective XCD-chunked swizzle (768=8x96).
//  attn_kernel : flash attention, FIXED-max exp2 softmax, in-register P.
//                R9 = R7 (best, 48.4us) + (1) v_cvt_pk_bf16_f32 packs
//                (24->8 VALU ops per (qs,sub); R7/R8 A-B showed wall tracks
//                VALU, not LDS reads) + (2) odd waves walk sub-tiles in
//                (1,0) order to de-phase the two waves per SIMD.

#define B_ 2
#define S_ 2048
#define D_ 1024
#define H_ 16
#define DH_ 64
#define M_ (B_*S_)   // 4096

#define WT_OFF  ((size_t)3*4194304)            // u16 offset of Wt
#define XB_OFF  (WT_OFF + (size_t)3*1048576)   // u16 offset of Xb slot (q)

typedef __attribute__((ext_vector_type(8))) short short8;
typedef __attribute__((ext_vector_type(4))) float f32x4;
typedef __attribute__((ext_vector_type(4))) unsigned int u32x4;
#define MFMA16(a,b,c) __builtin_amdgcn_mfma_f32_16x16x32_bf16(a,b,c,0,0,0)

typedef __attribute__((address_space(1))) const void* gptr_t;
typedef __attribute__((address_space(3))) void* lptr_t;
static __device__ inline void gload_lds16(const void* g, void* l) {
    __builtin_amdgcn_global_load_lds((gptr_t)g, (lptr_t)l, 16, 0, 0);
}

static __device__ inline unsigned short f2bf(float x) {   // RNE
    union { float f; unsigned u; } v; v.f = x;
    return (unsigned short)((v.u + 0x7fffu + ((v.u >> 16) & 1u)) >> 16);
}
// pack two floats to bf16 pair (round-half-up): 2 adds + 1 v_perm_b32
static __device__ inline unsigned packp(float a, float b) {
    return __builtin_amdgcn_perm(__float_as_uint(b) + 0x8000u,
                                 __float_as_uint(a) + 0x8000u, 0x07060302u);
}
// single-instruction pack (RNE): lo16 = bf(a), hi16 = bf(b)
static __device__ inline unsigned cvtpk(float a, float b) {
    unsigned r;
    asm("v_cvt_pk_bf16_f32 %0, %1, %2" : "=v"(r) : "v"(a), "v"(b));
    return r;
}

// ---------------------------------------------------------------------------
// Fused conversions. Grid (4096+256, 1, 3).
//   bx <  4096 : X (q/k/v) fp32 -> bf16, 1024 elems/block
//   bx >= 4096 : W fp32 [k][n] -> bf16 Wt [n][k], 64x64 tile via LDS
// ---------------------------------------------------------------------------
__global__ __launch_bounds__(256) void convert_all(
    const float* __restrict__ X0, const float* __restrict__ X1,
    const float* __restrict__ X2,
    const float* __restrict__ Wq, const float* __restrict__ Wk,
    const float* __restrict__ Wv,
    unsigned short* __restrict__ O0, unsigned short* __restrict__ O1,
    unsigned short* __restrict__ O2, unsigned short* __restrict__ WtBase)
{
    __shared__ unsigned short T[64][72];
    const int z = blockIdx.z;
    const int t = threadIdx.x;

    if (blockIdx.x < 4096) {
        const float* X = z==0 ? X0 : (z==1 ? X1 : X2);
        unsigned short* O = z==0 ? O0 : (z==1 ? O1 : O2);
        int idx = blockIdx.x*256 + t;
        float4 xv = *(const float4*)&X[(size_t)idx*4];
        uint2 o;
        o.x = (unsigned)f2bf(xv.x) | ((unsigned)f2bf(xv.y) << 16);
        o.y = (unsigned)f2bf(xv.z) | ((unsigned)f2bf(xv.w) << 16);
        *(uint2*)&O[(size_t)idx*4] = o;
        return;
    }

    const float* W = z==0 ? Wq : (z==1 ? Wk : Wv);
    unsigned short* Out = WtBase + ((size_t)z << 20);
    const int bx2 = blockIdx.x - 4096;
    const int n0 = (bx2 & 15)*64, k0 = (bx2 >> 4)*64;
    const int tk = t >> 4, tn4 = (t & 15)*4;

    #pragma unroll
    for (int i=0;i<4;i++){
        int kk = tk + i*16;
        float4 wv = *(const float4*)&W[(size_t)(k0+kk)*D_ + n0 + tn4];
        T[tn4+0][kk] = f2bf(wv.x);
        T[tn4+1][kk] = f2bf(wv.y);
        T[tn4+2][kk] = f2bf(wv.z);
        T[tn4+3][kk] = f2bf(wv.w);
    }
    __syncthreads();

    const int n = t >> 2, seg = t & 3;
    uint4 a = *(uint4*)&T[n][seg*16];
    uint4 b = *(uint4*)&T[n][seg*16 + 8];
    *(uint4*)&Out[(size_t)(n0+n)*D_ + k0 + seg*16]     = a;
    *(uint4*)&Out[(size_t)(n0+n)*D_ + k0 + seg*16 + 8] = b;
}

// ---------------------------------------------------------------------------
// Projection GEMM, pure-DMA staging, XOR-swizzled LDS. Grid (8,32,3).
// which==0: output scaled by log2e/32.  which==2: output transposed.
// XCD-chunked block swizzle: XCD k handles 12 contiguous (m,z)-panels.
// ---------------------------------------------------------------------------
__global__ __launch_bounds__(256) void proj_gemm(
    const unsigned short* __restrict__ A0, const unsigned short* __restrict__ A1,
    const unsigned short* __restrict__ A2, const unsigned short* __restrict__ WtBase,
    const float* __restrict__ b0, const float* __restrict__ b1,
    const float* __restrict__ b2, unsigned short* __restrict__ OutBase)
{
    // 768 blocks = 8 XCDs x 96. hw lin%8 ~ XCD -> give each XCD a contiguous
    // chunk of (x,y,z) linear space (12 A-panels x 8 B-tiles).
    const int lin0 = blockIdx.x + (blockIdx.y << 3) + (blockIdx.z << 8);
    const int swz  = (lin0 & 7)*96 + (lin0 >> 3);
    const int bxn  = swz & 7;
    const int byn  = (swz >> 3) & 31;
    const int which = swz >> 8;

    const unsigned short* A  = which==0 ? A0 : (which==1 ? A1 : A2);
    const unsigned short* Bm = WtBase + ((size_t)which << 20);
    const float* bias        = which==0 ? b0 : (which==1 ? b1 : b2);
    unsigned short* Out      = OutBase + ((size_t)which << 22);
    const float oscale = (which==0) ? 0.04508422f : 1.0f;   // log2e/32

    __shared__ __align__(16) unsigned short As[128*64];
    __shared__ __align__(16) unsigned short Bs[128*64];

    const int t    = threadIdx.x;
    const int m0   = byn * 128;
    const int n0   = bxn * 128;
    const int w    = t >> 6;
    const int lane = t & 63;
    const int l15  = lane & 15;
    const int quad = lane >> 4;
    const int wm   = w >> 1, wn = w & 1;

    f32x4 acc[4][4];
    #pragma unroll
    for (int i=0;i<4;i++)
        #pragma unroll
        for (int j=0;j<4;j++) acc[i][j] = (f32x4){0.f,0.f,0.f,0.f};

    float biasv[4];
    #pragma unroll
    for (int nt=0; nt<4; nt++)
        biasv[nt] = bias[n0 + wn*64 + nt*16 + l15];

    int sArow[4], sAkc[4];
    #pragma unroll
    for (int i=0;i<4;i++){
        int s  = (w*4 + i)*64 + lane;
        int r  = s >> 3, cs = s & 7;
        sArow[i] = r;
        sAkc[i]  = ((cs ^ (r & 7)) * 8);
    }

    for (int ks = 0; ks < 16; ++ks) {
        const int kb = ks * 64;
        #pragma unroll
        for (int i=0;i<4;i++){
            int s = (w*4 + i)*64 + lane;
            gload_lds16(A  + (size_t)(m0 + sArow[i])*D_ + kb + sAkc[i], (unsigned short*)As + s*8);
            gload_lds16(Bm + (size_t)(n0 + sArow[i])*D_ + kb + sAkc[i], (unsigned short*)Bs + s*8);
        }
        __syncthreads();

        #pragma unroll
        for (int kh=0; kh<2; kh++){
            short8 aF[4], bF[4];
            #pragma unroll
            for (int mt=0; mt<4; mt++){
                int r  = wm*64 + mt*16 + l15;
                int cs = (kh*4 + quad) ^ (r & 7);
                aF[mt] = *(const short8*)(As + r*64 + cs*8);
            }
            #pragma unroll
            for (int nt=0; nt<4; nt++){
                int r  = wn*64 + nt*16 + l15;
                int cs = (kh*4 + quad) ^ (r & 7);
                bF[nt] = *(const short8*)(Bs + r*64 + cs*8);
            }
            #pragma unroll
            for (int mt=0; mt<4; mt++)
                #pragma unroll
                for (int nt=0; nt<4; nt++)
                    acc[mt][nt] = MFMA16(aF[mt], bF[nt], acc[mt][nt]);
        }
        __syncthreads();
    }

    if (which != 2) {
        #pragma unroll
        for (int nt=0; nt<4; nt++){
            int n  = n0 + wn*64 + nt*16 + l15;
            int hh = n >> 6, dh = n & 63;
            #pragma unroll
            for (int mt=0; mt<4; mt++){
                #pragma unroll
                for (int r=0; r<4; r++){
                    int m  = m0 + wm*64 + mt*16 + quad*4 + r;
                    int bb = m >> 11, ss = m & (S_-1);
                    float v = (acc[mt][nt][r] + biasv[nt]) * oscale;
                    Out[((size_t)((bb*H_ + hh)*S_ + ss))*DH_ + dh] = f2bf(v);
                }
            }
        }
    } else {
        #pragma unroll
        for (int nt=0; nt<4; nt++){
            int n  = n0 + wn*64 + nt*16 + l15;
            int hh = n >> 6, dh = n & 63;
            #pragma unroll
            for (int mt=0; mt<4; mt++){
                int m  = m0 + wm*64 + mt*16 + quad*4;
                int bb = m >> 11, ss = m & (S_-1);
                uint2 pk;
                pk.x = packp(acc[mt][nt][0] + biasv[nt], acc[mt][nt][1] + biasv[nt]);
                pk.y = packp(acc[mt][nt][2] + biasv[nt], acc[mt][nt][3] + biasv[nt]);
                *(uint2*)&Out[((size_t)((bb*H_ + hh)*DH_ + dh))*S_ + ss] = pk;
            }
        }
    }
}

// ---------------------------------------------------------------------------
// Flash attention, fixed-max exp2 softmax, in-register P.
// Block = 256 q of one (b,h); 8 waves x 32 q (qs=2); each wave processes
// BOTH 64-key sub-tiles per 128-key iter (odd waves in (1,0) order for
// SIMD de-phasing). Grid (8,16,2) = 256 blocks = 1 block/CU = 2 waves/SIMD.
// One barrier per 128 keys. Static mask-bias table as QK MFMA C-init.
// XCD-swizzled (2MB K/V per XCD). Packs via v_cvt_pk_bf16_f32.
//
// Key-row permutation (per 64-key sub-tile): LDS K row l holds global key
//   g(l) = 32*(st&1) + 8*quad + 4*(st>>1) + r   (l = st*16+quad*4+r)
// so QK^T output sc[st][r] (lane quad) is the score of key 32(st&1)+8q+4(st>>1)+r,
// and {st0,st2} / {st1,st3} pack directly into pf0/pf1 (PV B-frag, k=quad*8+j).
// V^T is stored by TRUE key, matching the B-frag k index.
// ---------------------------------------------------------------------------
__global__ __launch_bounds__(512, 2) void attn_kernel(
    const unsigned short* __restrict__ ws, const int* __restrict__ mask,
    float* __restrict__ out)
{
    const unsigned short* Qh = ws;                      // [B][H][S][64], exp2-scaled
    const unsigned short* Kh = ws + (size_t)M_*D_;      // [B][H][S][64]
    const unsigned short* Vg = ws + 2*(size_t)M_*D_;    // [B][H][64][S]

    // XCD swizzle: XCD x gets 32 consecutive Wn = all 8 q-tiles of 4 heads
    // -> 2 MB K/V working set per XCD L2.
    const int lin = blockIdx.x + (blockIdx.y << 3) + (blockIdx.z << 7);
    const int Wn  = (lin & 7)*32 + (lin >> 3);
    const int qt = Wn & 7;
    const int h  = (Wn >> 3) & 15;
    const int bb = Wn >> 7;

    const size_t base = ((size_t)(bb*H_ + h)) * S_ * DH_;
    const int q0 = qt * 256;

    __shared__ __align__(16) unsigned char smem[73728];
    unsigned short* KsB = (unsigned short*)smem;            // [2][128][64] key-permuted
    unsigned short* VtB = (unsigned short*)(smem + 32768);  // [2][128][64] true-key order
    float*          MsT = (float*)(smem + 65536);           // [2048] static mask bias
    float*          Ob  = (float*)smem;                     // [256][68] f32 alias (epi)

    const int t    = threadIdx.x;    // 0..511
    const int w    = t >> 6;         // 0..7 -> q rows w*32..w*32+31
    const int lane = t & 63;
    const int l15  = lane & 15;
    const int quad = lane >> 4;

    short8 qf[2][2];
    #pragma unroll
    for (int qs=0; qs<2; qs++){
        const unsigned short* qp = Qh + base + (size_t)(q0 + w*32 + qs*16 + l15)*DH_ + quad*8;
        qf[qs][0] = *(const short8*)(qp);
        qf[qs][1] = *(const short8*)(qp + 32);
    }

    f32x4 accO[2][4];
    #pragma unroll
    for (int qs=0; qs<2; qs++)
        #pragma unroll
        for (int i=0;i<4;i++) accO[qs][i] = (f32x4){0.f,0.f,0.f,0.f};
    f32x4 lv[2] = {(f32x4){0.f,0.f,0.f,0.f}, (f32x4){0.f,0.f,0.f,0.f}};

    // staging: 8 waves x 2 slots x 64 lanes = 1024 slots of 16B per buffer.
    // slot row r in 0..127: sub-tile = r>>6, within-sub row = r&63.
    int rr[2], cc[2], ssl[2], gK[2];
    #pragma unroll
    for (int i=0;i<2;i++){
        int s  = (w*2 + i)*64 + lane;   // 0..1023
        int r  = s >> 3, cs = s & 7;
        int r6 = r & 63;
        ssl[i] = s;
        rr[i]  = r;
        cc[i]  = (cs ^ (r & 7)) * 8;
        gK[i]  = (r & 64) + ((r6 >> 4) & 1)*32 + ((r6 >> 2) & 3)*8 + (r6 >> 5)*4 + (r6 & 3);
    }

    #define ISSUE128(k0v, p) do {                                              \
        _Pragma("unroll")                                                      \
        for (int i=0;i<2;i++){                                                 \
            gload_lds16(Kh + base + (size_t)((k0v) + gK[i])*DH_ + cc[i],       \
                        KsB + (p)*8192 + ssl[i]*8);                            \
            gload_lds16(Vg + base + (size_t)(rr[i] & 63)*S_ + (k0v)            \
                            + (rr[i] & 64) + cc[i],                            \
                        VtB + (p)*8192 + ssl[i]*8);                            \
        }                                                                      \
    } while(0)

    // prologue: static mask-bias table + first DMA tile
    ISSUE128(0, 0);
    #pragma unroll
    for (int i=0;i<4;i++){
        int idx = i*512 + t;
        MsT[idx] = mask[bb*S_ + idx] ? 0.f : -1e9f;
    }
    __syncthreads();

    for (int it = 0; it < 16; ++it){
        const int p = it & 1;
        if (it < 15) ISSUE128((it+1)*128, 1-p);

        #pragma unroll
        for (int sbi = 0; sbi < 2; ++sbi){
            const int sb = sbi ^ (w & 1);    // de-phase the 2 waves per SIMD
            const unsigned short* Ks  = KsB + p*8192 + sb*4096;
            const unsigned short* Vts = VtB + p*8192 + sb*4096;
            const float*          Mp  = MsT + it*128 + sb*64;

            // mask bias in permuted-key order (MFMA C-init):
            // key(st,quad,r) = 32(st&1)+4(st>>1)+8quad+r
            f32x4 msv[4];
            #pragma unroll
            for (int st=0; st<4; st++)
                msv[st] = *(const f32x4*)&Mp[(st&1)*32 + (st>>1)*4 + quad*8];

            // K/V fragments: loaded ONCE per sub-tile, shared by both qs
            short8 ka[4], kb[4];
            #pragma unroll
            for (int st=0; st<4; st++){
                int row = st*16 + l15;
                const unsigned short* kr = Ks + row*64;
                ka[st] = *(const short8*)(kr + ((quad    ) ^ (row & 7))*8);
                kb[st] = *(const short8*)(kr + ((quad + 4) ^ (row & 7))*8);
            }
            short8 vf[4][2];
            #pragma unroll
            for (int mt=0; mt<4; mt++){
                int row = mt*16 + l15;
                const unsigned short* vr = Vts + row*64;
                vf[mt][0] = *(const short8*)(vr + ((quad    ) ^ (row & 7))*8);
                vf[mt][1] = *(const short8*)(vr + ((quad + 4) ^ (row & 7))*8);
            }

            #pragma unroll
            for (int qs=0; qs<2; qs++){
                // ---- scores: S^T = K·Q^T, mask bias as accumulator init ----
                f32x4 sc[4];
                __builtin_amdgcn_s_setprio(1);
                #pragma unroll
                for (int st=0; st<4; st++){
                    f32x4 a = msv[st];
                    a = MFMA16(ka[st], qf[qs][0], a);
                    a = MFMA16(kb[st], qf[qs][1], a);
                    sc[st] = a;
                }
                __builtin_amdgcn_s_setprio(0);
                // ---- fixed-max softmax, tree-summed l, packed into B-frag ----
                f32x4 pvv[4];
                #pragma unroll
                for (int st=0; st<4; st++)
                    #pragma unroll
                    for (int rj=0; rj<4; rj++)
                        pvv[st][rj] = __builtin_amdgcn_exp2f(sc[st][rj]);
                f32x4 s01 = pvv[0] + pvv[1];
                f32x4 s23 = pvv[2] + pvv[3];
                lv[qs] += (s01 + s23);
                u32x4 u0 = { cvtpk(pvv[0][0],pvv[0][1]), cvtpk(pvv[0][2],pvv[0][3]),
                             cvtpk(pvv[2][0],pvv[2][1]), cvtpk(pvv[2][2],pvv[2][3]) };
                u32x4 u1 = { cvtpk(pvv[1][0],pvv[1][1]), cvtpk(pvv[1][2],pvv[1][3]),
                             cvtpk(pvv[3][0],pvv[3][1]), cvtpk(pvv[3][2],pvv[3][3]) };
                short8 pf0 = __builtin_bit_cast(short8, u0);
                short8 pf1 = __builtin_bit_cast(short8, u1);
                // ---- PV: O^T += V^T · P^T (P entirely in registers) ----
                __builtin_amdgcn_s_setprio(1);
                #pragma unroll
                for (int mt=0; mt<4; mt++){
                    accO[qs][mt] = MFMA16(vf[mt][0], pf0, accO[qs][mt]);
                    accO[qs][mt] = MFMA16(vf[mt][1], pf1, accO[qs][mt]);
                }
                __builtin_amdgcn_s_setprio(0);
            }
        }
        __syncthreads();
    }

    // ---- epilogue: reduce l across quads ONCE, normalize, transpose, store ----
    #pragma unroll
    for (int qs=0; qs<2; qs++){
        float l = (lv[qs][0] + lv[qs][1]) + (lv[qs][2] + lv[qs][3]);
        l += __shfl_xor(l, 16);
        l += __shfl_xor(l, 32);
        float invl = 1.0f / fmaxf(l, 1e-30f);
        #pragma unroll
        for (int mt=0; mt<4; mt++)
            #pragma unroll
            for (int r=0; r<4; r++)
                Ob[(w*32 + qs*16 + l15)*68 + mt*16 + quad*4 + r] = accO[qs][mt][r]*invl;
    }
    __syncthreads();

    #pragma unroll
    for (int i=0;i<8;i++){
        int f  = (i*512 + t)*4;
        int qq = f >> 6, dh = f & 63;
        float4 o = *(float4*)&Ob[qq*68 + dh];
        *(float4*)&out[((size_t)(bb*S_ + q0 + qq))*D_ + h*DH_ + dh] = o;
    }
    #undef ISSUE128
}

extern "C" void kernel_launch(void* const* d_in, const int* in_sizes, int n_in,
                              void* d_out, int out_size, void* d_ws, size_t ws_size,
                              hipStream_t stream) {
    const float* q    = (const float*)d_in[0];
    const float* k    = (const float*)d_in[1];
    const float* v    = (const float*)d_in[2];
    const int*   mask = (const int*)d_in[3];
    const float* Wq   = (const float*)d_in[4];
    const float* b0   = (const float*)d_in[5];
    const float* Wk   = (const float*)d_in[6];
    const float* b1   = (const float*)d_in[7];
    const float* Wv   = (const float*)d_in[8];
    const float* b2   = (const float*)d_in[9];
    float* out = (float*)d_out;
    unsigned short* ws = (unsigned short*)d_ws;   // 39.85 MB used

    // Xb slots: q -> ws; k,v -> d_out (scratch until attn overwrites it last)
    unsigned short* xq = ws + XB_OFF;
    unsigned short* xk = (unsigned short*)d_out;
    unsigned short* xv = (unsigned short*)d_out + 4194304;

    convert_all<<<dim3(4352,1,3), 256, 0, stream>>>(q, k, v, Wq, Wk, Wv,
                                                    xq, xk, xv, ws + WT_OFF);
    proj_gemm<<<dim3(8,32,3), 256, 0, stream>>>(xq, xk, xv, ws + WT_OFF,
                                                b0, b1, b2, ws);
    attn_kernel<<<dim3(8,16,2), 512, 0, stream>>>(ws, mask, out);
}

// Round 10
// 190.291 us; speedup vs baseline: 1.0587x; 1.0330x over previous
//
#include <hip/hip_runtime.h>

// B=2, S=2048, D=1024, H=16, DH=64.
// 3 launches:
//  convert_all : fused W transpose->bf16 and q/k/v fp32->bf16 (8 elem/thread).
//  proj_gemm   : z=3, Outh[w] = Xb @ Wt^T + bias. which==0 pre-scaled by
//                log2e/32; which==2 stored transposed. XCD-chunked swizzle.
//                R10: explicit LDS double-buffer, counted s_waitcnt vmcnt(8)
//                + raw s_barrier (next tile's DMA stays in flight across the
//                barrier -- removes the per-K-step vmcnt(0) drain that
//                serialized ~1000cyc/step at this short-K shape).
//  attn_kernel : unchanged from R9 (best, ~46us).

#define B_ 2
#define S_ 2048
#define D_ 1024
#define H_ 16
#define DH_ 64
#define M_ (B_*S_)   // 4096

#define WT_OFF  ((size_t)3*4194304)            // u16 offset of Wt
#define XB_OFF  (WT_OFF + (size_t)3*1048576)   // u16 offset of Xb slot (q)

typedef __attribute__((ext_vector_type(8))) short short8;
typedef __attribute__((ext_vector_type(4))) float f32x4;
typedef __attribute__((ext_vector_type(4))) unsigned int u32x4;
#define MFMA16(a,b,c) __builtin_amdgcn_mfma_f32_16x16x32_bf16(a,b,c,0,0,0)

typedef __attribute__((address_space(1))) const void* gptr_t;
typedef __attribute__((address_space(3))) void* lptr_t;
static __device__ inline void gload_lds16(const void* g, void* l) {
    __builtin_amdgcn_global_load_lds((gptr_t)g, (lptr_t)l, 16, 0, 0);
}

static __device__ inline unsigned short f2bf(float x) {   // RNE
    union { float f; unsigned u; } v; v.f = x;
    return (unsigned short)((v.u + 0x7fffu + ((v.u >> 16) & 1u)) >> 16);
}
// pack two floats to bf16 pair (round-half-up): 2 adds + 1 v_perm_b32
static __device__ inline unsigned packp(float a, float b) {
    return __builtin_amdgcn_perm(__float_as_uint(b) + 0x8000u,
                                 __float_as_uint(a) + 0x8000u, 0x07060302u);
}
// single-instruction pack (RNE): lo16 = bf(a), hi16 = bf(b)
static __device__ inline unsigned cvtpk(float a, float b) {
    unsigned r;
    asm("v_cvt_pk_bf16_f32 %0, %1, %2" : "=v"(r) : "v"(a), "v"(b));
    return r;
}

// ---------------------------------------------------------------------------
// Fused conversions. Grid (2048+256, 1, 3).
//   bx <  2048 : X (q/k/v) fp32 -> bf16, 2048 elems/block (8/thread)
//   bx >= 2048 : W fp32 [k][n] -> bf16 Wt [n][k], 64x64 tile via LDS
// ---------------------------------------------------------------------------
__global__ __launch_bounds__(256) void convert_all(
    const float* __restrict__ X0, const float* __restrict__ X1,
    const float* __restrict__ X2,
    const float* __restrict__ Wq, const float* __restrict__ Wk,
    const float* __restrict__ Wv,
    unsigned short* __restrict__ O0, unsigned short* __restrict__ O1,
    unsigned short* __restrict__ O2, unsigned short* __restrict__ WtBase)
{
    __shared__ unsigned short T[64][72];
    const int z = blockIdx.z;
    const int t = threadIdx.x;

    if (blockIdx.x < 2048) {
        const float* X = z==0 ? X0 : (z==1 ? X1 : X2);
        unsigned short* O = z==0 ? O0 : (z==1 ? O1 : O2);
        size_t e = ((size_t)(blockIdx.x*256 + t))*8;
        float4 a = *(const float4*)&X[e];
        float4 b = *(const float4*)&X[e+4];
        uint4 o;
        o.x = (unsigned)f2bf(a.x) | ((unsigned)f2bf(a.y) << 16);
        o.y = (unsigned)f2bf(a.z) | ((unsigned)f2bf(a.w) << 16);
        o.z = (unsigned)f2bf(b.x) | ((unsigned)f2bf(b.y) << 16);
        o.w = (unsigned)f2bf(b.z) | ((unsigned)f2bf(b.w) << 16);
        *(uint4*)&O[e] = o;
        return;
    }

    const float* W = z==0 ? Wq : (z==1 ? Wk : Wv);
    unsigned short* Out = WtBase + ((size_t)z << 20);
    const int bx2 = blockIdx.x - 2048;
    const int n0 = (bx2 & 15)*64, k0 = (bx2 >> 4)*64;
    const int tk = t >> 4, tn4 = (t & 15)*4;

    #pragma unroll
    for (int i=0;i<4;i++){
        int kk = tk + i*16;
        float4 wv = *(const float4*)&W[(size_t)(k0+kk)*D_ + n0 + tn4];
        T[tn4+0][kk] = f2bf(wv.x);
        T[tn4+1][kk] = f2bf(wv.y);
        T[tn4+2][kk] = f2bf(wv.z);
        T[tn4+3][kk] = f2bf(wv.w);
    }
    __syncthreads();

    const int n = t >> 2, seg = t & 3;
    uint4 a = *(uint4*)&T[n][seg*16];
    uint4 b = *(uint4*)&T[n][seg*16 + 8];
    *(uint4*)&Out[(size_t)(n0+n)*D_ + k0 + seg*16]     = a;
    *(uint4*)&Out[(size_t)(n0+n)*D_ + k0 + seg*16 + 8] = b;
}

// ---------------------------------------------------------------------------
// Projection GEMM, pure-DMA staging, XOR-swizzled LDS, DOUBLE-BUFFERED.
// Grid (8,32,3). which==0: scaled by log2e/32. which==2: transposed output.
// XCD-chunked block swizzle. Counted vmcnt (8 = next tile's loads) + raw
// s_barrier: the next K-tile's DMA stays in flight across the barrier.
// ---------------------------------------------------------------------------
__global__ __launch_bounds__(256) void proj_gemm(
    const unsigned short* __restrict__ A0, const unsigned short* __restrict__ A1,
    const unsigned short* __restrict__ A2, const unsigned short* __restrict__ WtBase,
    const float* __restrict__ b0, const float* __restrict__ b1,
    const float* __restrict__ b2, unsigned short* __restrict__ OutBase)
{
    // 768 blocks = 8 XCDs x 96: each XCD a contiguous chunk of (x,y,z) space.
    const int lin0 = blockIdx.x + (blockIdx.y << 3) + (blockIdx.z << 8);
    const int swz  = (lin0 & 7)*96 + (lin0 >> 3);
    const int bxn  = swz & 7;
    const int byn  = (swz >> 3) & 31;
    const int which = swz >> 8;

    const unsigned short* A  = which==0 ? A0 : (which==1 ? A1 : A2);
    const unsigned short* Bm = WtBase + ((size_t)which << 20);
    const float* bias        = which==0 ? b0 : (which==1 ? b1 : b2);
    unsigned short* Out      = OutBase + ((size_t)which << 22);
    const float oscale = (which==0) ? 0.04508422f : 1.0f;   // log2e/32

    __shared__ __align__(16) unsigned short As[2*128*64];
    __shared__ __align__(16) unsigned short Bs[2*128*64];

    const int t    = threadIdx.x;
    const int m0   = byn * 128;
    const int n0   = bxn * 128;
    const int w    = t >> 6;
    const int lane = t & 63;
    const int l15  = lane & 15;
    const int quad = lane >> 4;
    const int wm   = w >> 1, wn = w & 1;

    f32x4 acc[4][4];
    #pragma unroll
    for (int i=0;i<4;i++)
        #pragma unroll
        for (int j=0;j<4;j++) acc[i][j] = (f32x4){0.f,0.f,0.f,0.f};

    // biasv loaded FIRST: oldest in the vmem queue, subsumed by vmcnt(8)
    float biasv[4];
    #pragma unroll
    for (int nt=0; nt<4; nt++)
        biasv[nt] = bias[n0 + wn*64 + nt*16 + l15];

    int sArow[4], sAkc[4];
    #pragma unroll
    for (int i=0;i<4;i++){
        int s  = (w*4 + i)*64 + lane;
        int r  = s >> 3, cs = s & 7;
        sArow[i] = r;
        sAkc[i]  = ((cs ^ (r & 7)) * 8);
    }

    #define PISSUE(ksv, buf) do {                                              \
        const int kb = (ksv)*64;                                               \
        _Pragma("unroll")                                                      \
        for (int i=0;i<4;i++){                                                 \
            int s = (w*4 + i)*64 + lane;                                       \
            gload_lds16(A  + (size_t)(m0 + sArow[i])*D_ + kb + sAkc[i],        \
                        (unsigned short*)As + (buf)*8192 + s*8);               \
            gload_lds16(Bm + (size_t)(n0 + sArow[i])*D_ + kb + sAkc[i],        \
                        (unsigned short*)Bs + (buf)*8192 + s*8);               \
        }                                                                      \
    } while(0)

    PISSUE(0, 0);
    int cur = 0;
    for (int ks = 0; ks < 16; ++ks) {
        if (ks < 15) {
            PISSUE(ks+1, cur^1);                          // 8 loads in flight
            asm volatile("s_waitcnt vmcnt(8)" ::: "memory");  // cur tile done
        } else {
            asm volatile("s_waitcnt vmcnt(0)" ::: "memory");
        }
        __builtin_amdgcn_s_barrier();
        __builtin_amdgcn_sched_barrier(0);

        const unsigned short* Asb = As + cur*8192;
        const unsigned short* Bsb = Bs + cur*8192;
        #pragma unroll
        for (int kh=0; kh<2; kh++){
            short8 aF[4], bF[4];
            #pragma unroll
            for (int mt=0; mt<4; mt++){
                int r  = wm*64 + mt*16 + l15;
                int cs = (kh*4 + quad) ^ (r & 7);
                aF[mt] = *(const short8*)(Asb + r*64 + cs*8);
            }
            #pragma unroll
            for (int nt=0; nt<4; nt++){
                int r  = wn*64 + nt*16 + l15;
                int cs = (kh*4 + quad) ^ (r & 7);
                bF[nt] = *(const short8*)(Bsb + r*64 + cs*8);
            }
            #pragma unroll
            for (int mt=0; mt<4; mt++)
                #pragma unroll
                for (int nt=0; nt<4; nt++)
                    acc[mt][nt] = MFMA16(aF[mt], bF[nt], acc[mt][nt]);
        }
        __builtin_amdgcn_s_barrier();   // all readers of cur done before overwrite
        cur ^= 1;
    }

    if (which != 2) {
        #pragma unroll
        for (int nt=0; nt<4; nt++){
            int n  = n0 + wn*64 + nt*16 + l15;
            int hh = n >> 6, dh = n & 63;
            #pragma unroll
            for (int mt=0; mt<4; mt++){
                #pragma unroll
                for (int r=0; r<4; r++){
                    int m  = m0 + wm*64 + mt*16 + quad*4 + r;
                    int bb = m >> 11, ss = m & (S_-1);
                    float v = (acc[mt][nt][r] + biasv[nt]) * oscale;
                    Out[((size_t)((bb*H_ + hh)*S_ + ss))*DH_ + dh] = f2bf(v);
                }
            }
        }
    } else {
        #pragma unroll
        for (int nt=0; nt<4; nt++){
            int n  = n0 + wn*64 + nt*16 + l15;
            int hh = n >> 6, dh = n & 63;
            #pragma unroll
            for (int mt=0; mt<4; mt++){
                int m  = m0 + wm*64 + mt*16 + quad*4;
                int bb = m >> 11, ss = m & (S_-1);
                uint2 pk;
                pk.x = packp(acc[mt][nt][0] + biasv[nt], acc[mt][nt][1] + biasv[nt]);
                pk.y = packp(acc[mt][nt][2] + biasv[nt], acc[mt][nt][3] + biasv[nt]);
                *(uint2*)&Out[((size_t)((bb*H_ + hh)*DH_ + dh))*S_ + ss] = pk;
            }
        }
    }
    #undef PISSUE
}

// ---------------------------------------------------------------------------
// Flash attention (unchanged from R9): fixed-max exp2 softmax, in-register P.
// Block = 256 q of one (b,h); 8 waves x 32 q (qs=2); both 64-key sub-tiles
// per wave (odd waves in (1,0) order). Grid (8,16,2) = 1 block/CU.
// ---------------------------------------------------------------------------
__global__ __launch_bounds__(512, 2) void attn_kernel(
    const unsigned short* __restrict__ ws, const int* __restrict__ mask,
    float* __restrict__ out)
{
    const unsigned short* Qh = ws;                      // [B][H][S][64], exp2-scaled
    const unsigned short* Kh = ws + (size_t)M_*D_;      // [B][H][S][64]
    const unsigned short* Vg = ws + 2*(size_t)M_*D_;    // [B][H][64][S]

    const int lin = blockIdx.x + (blockIdx.y << 3) + (blockIdx.z << 7);
    const int Wn  = (lin & 7)*32 + (lin >> 3);
    const int qt = Wn & 7;
    const int h  = (Wn >> 3) & 15;
    const int bb = Wn >> 7;

    const size_t base = ((size_t)(bb*H_ + h)) * S_ * DH_;
    const int q0 = qt * 256;

    __shared__ __align__(16) unsigned char smem[73728];
    unsigned short* KsB = (unsigned short*)smem;            // [2][128][64] key-permuted
    unsigned short* VtB = (unsigned short*)(smem + 32768);  // [2][128][64] true-key order
    float*          MsT = (float*)(smem + 65536);           // [2048] static mask bias
    float*          Ob  = (float*)smem;                     // [256][68] f32 alias (epi)

    const int t    = threadIdx.x;    // 0..511
    const int w    = t >> 6;         // 0..7 -> q rows w*32..w*32+31
    const int lane = t & 63;
    const int l15  = lane & 15;
    const int quad = lane >> 4;

    short8 qf[2][2];
    #pragma unroll
    for (int qs=0; qs<2; qs++){
        const unsigned short* qp = Qh + base + (size_t)(q0 + w*32 + qs*16 + l15)*DH_ + quad*8;
        qf[qs][0] = *(const short8*)(qp);
        qf[qs][1] = *(const short8*)(qp + 32);
    }

    f32x4 accO[2][4];
    #pragma unroll
    for (int qs=0; qs<2; qs++)
        #pragma unroll
        for (int i=0;i<4;i++) accO[qs][i] = (f32x4){0.f,0.f,0.f,0.f};
    f32x4 lv[2] = {(f32x4){0.f,0.f,0.f,0.f}, (f32x4){0.f,0.f,0.f,0.f}};

    int rr[2], cc[2], ssl[2], gK[2];
    #pragma unroll
    for (int i=0;i<2;i++){
        int s  = (w*2 + i)*64 + lane;   // 0..1023
        int r  = s >> 3, cs = s & 7;
        int r6 = r & 63;
        ssl[i] = s;
        rr[i]  = r;
        cc[i]  = (cs ^ (r & 7)) * 8;
        gK[i]  = (r & 64) + ((r6 >> 4) & 1)*32 + ((r6 >> 2) & 3)*8 + (r6 >> 5)*4 + (r6 & 3);
    }

    #define ISSUE128(k0v, p) do {                                              \
        _Pragma("unroll")                                                      \
        for (int i=0;i<2;i++){                                                 \
            gload_lds16(Kh + base + (size_t)((k0v) + gK[i])*DH_ + cc[i],       \
                        KsB + (p)*8192 + ssl[i]*8);                            \
            gload_lds16(Vg + base + (size_t)(rr[i] & 63)*S_ + (k0v)            \
                            + (rr[i] & 64) + cc[i],                            \
                        VtB + (p)*8192 + ssl[i]*8);                            \
        }                                                                      \
    } while(0)

    ISSUE128(0, 0);
    #pragma unroll
    for (int i=0;i<4;i++){
        int idx = i*512 + t;
        MsT[idx] = mask[bb*S_ + idx] ? 0.f : -1e9f;
    }
    __syncthreads();

    for (int it = 0; it < 16; ++it){
        const int p = it & 1;
        if (it < 15) ISSUE128((it+1)*128, 1-p);

        #pragma unroll
        for (int sbi = 0; sbi < 2; ++sbi){
            const int sb = sbi ^ (w & 1);    // de-phase the 2 waves per SIMD
            const unsigned short* Ks  = KsB + p*8192 + sb*4096;
            const unsigned short* Vts = VtB + p*8192 + sb*4096;
            const float*          Mp  = MsT + it*128 + sb*64;

            f32x4 msv[4];
            #pragma unroll
            for (int st=0; st<4; st++)
                msv[st] = *(const f32x4*)&Mp[(st&1)*32 + (st>>1)*4 + quad*8];

            short8 ka[4], kb[4];
            #pragma unroll
            for (int st=0; st<4; st++){
                int row = st*16 + l15;
                const unsigned short* kr = Ks + row*64;
                ka[st] = *(const short8*)(kr + ((quad    ) ^ (row & 7))*8);
                kb[st] = *(const short8*)(kr + ((quad + 4) ^ (row & 7))*8);
            }
            short8 vf[4][2];
            #pragma unroll
            for (int mt=0; mt<4; mt++){
                int row = mt*16 + l15;
                const unsigned short* vr = Vts + row*64;
                vf[mt][0] = *(const short8*)(vr + ((quad    ) ^ (row & 7))*8);
                vf[mt][1] = *(const short8*)(vr + ((quad + 4) ^ (row & 7))*8);
            }

            #pragma unroll
            for (int qs=0; qs<2; qs++){
                f32x4 sc[4];
                __builtin_amdgcn_s_setprio(1);
                #pragma unroll
                for (int st=0; st<4; st++){
                    f32x4 a = msv[st];
                    a = MFMA16(ka[st], qf[qs][0], a);
                    a = MFMA16(kb[st], qf[qs][1], a);
                    sc[st] = a;
                }
                __builtin_amdgcn_s_setprio(0);
                f32x4 pvv[4];
                #pragma unroll
                for (int st=0; st<4; st++)
                    #pragma unroll
                    for (int rj=0; rj<4; rj++)
                        pvv[st][rj] = __builtin_amdgcn_exp2f(sc[st][rj]);
                f32x4 s01 = pvv[0] + pvv[1];
                f32x4 s23 = pvv[2] + pvv[3];
                lv[qs] += (s01 + s23);
                u32x4 u0 = { cvtpk(pvv[0][0],pvv[0][1]), cvtpk(pvv[0][2],pvv[0][3]),
                             cvtpk(pvv[2][0],pvv[2][1]), cvtpk(pvv[2][2],pvv[2][3]) };
                u32x4 u1 = { cvtpk(pvv[1][0],pvv[1][1]), cvtpk(pvv[1][2],pvv[1][3]),
                             cvtpk(pvv[3][0],pvv[3][1]), cvtpk(pvv[3][2],pvv[3][3]) };
                short8 pf0 = __builtin_bit_cast(short8, u0);
                short8 pf1 = __builtin_bit_cast(short8, u1);
                __builtin_amdgcn_s_setprio(1);
                #pragma unroll
                for (int mt=0; mt<4; mt++){
                    accO[qs][mt] = MFMA16(vf[mt][0], pf0, accO[qs][mt]);
                    accO[qs][mt] = MFMA16(vf[mt][1], pf1, accO[qs][mt]);
                }
                __builtin_amdgcn_s_setprio(0);
            }
        }
        __syncthreads();
    }

    #pragma unroll
    for (int qs=0; qs<2; qs++){
        float l = (lv[qs][0] + lv[qs][1]) + (lv[qs][2] + lv[qs][3]);
        l += __shfl_xor(l, 16);
        l += __shfl_xor(l, 32);
        float invl = 1.0f / fmaxf(l, 1e-30f);
        #pragma unroll
        for (int mt=0; mt<4; mt++)
            #pragma unroll
            for (int r=0; r<4; r++)
                Ob[(w*32 + qs*16 + l15)*68 + mt*16 + quad*4 + r] = accO[qs][mt][r]*invl;
    }
    __syncthreads();

    #pragma unroll
    for (int i=0;i<8;i++){
        int f  = (i*512 + t)*4;
        int qq = f >> 6, dh = f & 63;
        float4 o = *(float4*)&Ob[qq*68 + dh];
        *(float4*)&out[((size_t)(bb*S_ + q0 + qq))*D_ + h*DH_ + dh] = o;
    }
    #undef ISSUE128
}

extern "C" void kernel_launch(void* const* d_in, const int* in_sizes, int n_in,
                              void* d_out, int out_size, void* d_ws, size_t ws_size,
                              hipStream_t stream) {
    const float* q    = (const float*)d_in[0];
    const float* k    = (const float*)d_in[1];
    const float* v    = (const float*)d_in[2];
    const int*   mask = (const int*)d_in[3];
    const float* Wq   = (const float*)d_in[4];
    const float* b0   = (const float*)d_in[5];
    const float* Wk   = (const float*)d_in[6];
    const float* b1   = (const float*)d_in[7];
    const float* Wv   = (const float*)d_in[8];
    const float* b2   = (const float*)d_in[9];
    float* out = (float*)d_out;
    unsigned short* ws = (unsigned short*)d_ws;   // 39.85 MB used

    // Xb slots: q -> ws; k,v -> d_out (scratch until attn overwrites it last)
    unsigned short* xq = ws + XB_OFF;
    unsigned short* xk = (unsigned short*)d_out;
    unsigned short* xv = (unsigned short*)d_out + 4194304;

    convert_all<<<dim3(2304,1,3), 256, 0, stream>>>(q, k, v, Wq, Wk, Wv,
                                                    xq, xk, xv, ws + WT_OFF);
    proj_gemm<<<dim3(8,32,3), 256, 0, stream>>>(xq, xk, xv, ws + WT_OFF,
                                                b0, b1, b2, ws);
    attn_kernel<<<dim3(8,16,2), 512, 0, stream>>>(ws, mask, out);
}

// Round 11
// 188.300 us; speedup vs baseline: 1.0699x; 1.0106x over previous
//
#include <hip/hip_runtime.h>

// B=2, S=2048, D=1024, H=16, DH=64.
// 3 launches:
//  convert_all : fused W transpose->bf16 and q/k/v fp32->bf16 (8 elem/thread).
//  proj_gemm   : R11: 64x128 tiles, 1536 tiles = 512 blocks x 3 (static,
//                uniform, zero atomics) -- kills the 768-block 1.5-round
//                dispatch quantization (25% idle). Same dbuf + counted
//                vmcnt (6 = next tile's loads) + raw barrier as R10.
//                Static XCD locality: tile id ((z*64+m)*8+n); XCD x owns
//                [x*192,(x+1)*192) matching hw blockIdx%8.
//  attn_kernel : unchanged from R10 (best, 45.4us).

#define B_ 2
#define S_ 2048
#define D_ 1024
#define H_ 16
#define DH_ 64
#define M_ (B_*S_)   // 4096

#define WT_OFF  ((size_t)3*4194304)            // u16 offset of Wt
#define XB_OFF  (WT_OFF + (size_t)3*1048576)   // u16 offset of Xb slot (q)

typedef __attribute__((ext_vector_type(8))) short short8;
typedef __attribute__((ext_vector_type(4))) float f32x4;
typedef __attribute__((ext_vector_type(4))) unsigned int u32x4;
#define MFMA16(a,b,c) __builtin_amdgcn_mfma_f32_16x16x32_bf16(a,b,c,0,0,0)

typedef __attribute__((address_space(1))) const void* gptr_t;
typedef __attribute__((address_space(3))) void* lptr_t;
static __device__ inline void gload_lds16(const void* g, void* l) {
    __builtin_amdgcn_global_load_lds((gptr_t)g, (lptr_t)l, 16, 0, 0);
}

static __device__ inline unsigned short f2bf(float x) {   // RNE
    union { float f; unsigned u; } v; v.f = x;
    return (unsigned short)((v.u + 0x7fffu + ((v.u >> 16) & 1u)) >> 16);
}
// pack two floats to bf16 pair (round-half-up): 2 adds + 1 v_perm_b32
static __device__ inline unsigned packp(float a, float b) {
    return __builtin_amdgcn_perm(__float_as_uint(b) + 0x8000u,
                                 __float_as_uint(a) + 0x8000u, 0x07060302u);
}
// single-instruction pack (RNE): lo16 = bf(a), hi16 = bf(b)
static __device__ inline unsigned cvtpk(float a, float b) {
    unsigned r;
    asm("v_cvt_pk_bf16_f32 %0, %1, %2" : "=v"(r) : "v"(a), "v"(b));
    return r;
}

// ---------------------------------------------------------------------------
// Fused conversions. Grid (2048+256, 1, 3).
//   bx <  2048 : X (q/k/v) fp32 -> bf16, 2048 elems/block (8/thread)
//   bx >= 2048 : W fp32 [k][n] -> bf16 Wt [n][k], 64x64 tile via LDS
// ---------------------------------------------------------------------------
__global__ __launch_bounds__(256) void convert_all(
    const float* __restrict__ X0, const float* __restrict__ X1,
    const float* __restrict__ X2,
    const float* __restrict__ Wq, const float* __restrict__ Wk,
    const float* __restrict__ Wv,
    unsigned short* __restrict__ O0, unsigned short* __restrict__ O1,
    unsigned short* __restrict__ O2, unsigned short* __restrict__ WtBase)
{
    __shared__ unsigned short T[64][72];
    const int z = blockIdx.z;
    const int t = threadIdx.x;

    if (blockIdx.x < 2048) {
        const float* X = z==0 ? X0 : (z==1 ? X1 : X2);
        unsigned short* O = z==0 ? O0 : (z==1 ? O1 : O2);
        size_t e = ((size_t)(blockIdx.x*256 + t))*8;
        float4 a = *(const float4*)&X[e];
        float4 b = *(const float4*)&X[e+4];
        uint4 o;
        o.x = (unsigned)f2bf(a.x) | ((unsigned)f2bf(a.y) << 16);
        o.y = (unsigned)f2bf(a.z) | ((unsigned)f2bf(a.w) << 16);
        o.z = (unsigned)f2bf(b.x) | ((unsigned)f2bf(b.y) << 16);
        o.w = (unsigned)f2bf(b.z) | ((unsigned)f2bf(b.w) << 16);
        *(uint4*)&O[e] = o;
        return;
    }

    const float* W = z==0 ? Wq : (z==1 ? Wk : Wv);
    unsigned short* Out = WtBase + ((size_t)z << 20);
    const int bx2 = blockIdx.x - 2048;
    const int n0 = (bx2 & 15)*64, k0 = (bx2 >> 4)*64;
    const int tk = t >> 4, tn4 = (t & 15)*4;

    #pragma unroll
    for (int i=0;i<4;i++){
        int kk = tk + i*16;
        float4 wv = *(const float4*)&W[(size_t)(k0+kk)*D_ + n0 + tn4];
        T[tn4+0][kk] = f2bf(wv.x);
        T[tn4+1][kk] = f2bf(wv.y);
        T[tn4+2][kk] = f2bf(wv.z);
        T[tn4+3][kk] = f2bf(wv.w);
    }
    __syncthreads();

    const int n = t >> 2, seg = t & 3;
    uint4 a = *(uint4*)&T[n][seg*16];
    uint4 b = *(uint4*)&T[n][seg*16 + 8];
    *(uint4*)&Out[(size_t)(n0+n)*D_ + k0 + seg*16]     = a;
    *(uint4*)&Out[(size_t)(n0+n)*D_ + k0 + seg*16 + 8] = b;
}

// ---------------------------------------------------------------------------
// Projection GEMM, 64x128 tiles, 512 blocks x 3 tiles (uniform, single
// dispatch round at 2 blocks/CU). Pure-DMA dbuf staging, XOR-swizzled LDS,
// counted vmcnt(6) + raw s_barrier. Tile id = ((z*64+m)*8+n); block b
// (hw XCD = b&7) owns ids xcd*192 + slot + {0,64,128}.
// which==0: output scaled by log2e/32. which==2: transposed output.
// ---------------------------------------------------------------------------
__global__ __launch_bounds__(256) void proj_gemm(
    const unsigned short* __restrict__ A0, const unsigned short* __restrict__ A1,
    const unsigned short* __restrict__ A2, const unsigned short* __restrict__ WtBase,
    const float* __restrict__ b0, const float* __restrict__ b1,
    const float* __restrict__ b2, unsigned short* __restrict__ OutBase)
{
    const int blk  = blockIdx.x;
    const int xcd  = blk & 7;
    const int slot = blk >> 3;

    __shared__ __align__(16) unsigned short As[2*64*64];    // 16 KB
    __shared__ __align__(16) unsigned short Bs[2*128*64];   // 32 KB

    const int t    = threadIdx.x;
    const int w    = t >> 6;
    const int lane = t & 63;
    const int l15  = lane & 15;
    const int quad = lane >> 4;

    // staging slot geometry (tile-independent)
    int aR[2], aC[2], aS[2];
    #pragma unroll
    for (int i=0;i<2;i++){
        int s = (w*2 + i)*64 + lane;        // 0..511
        int r = s >> 3, cs = s & 7;
        aS[i] = s; aR[i] = r; aC[i] = ((cs ^ (r & 7)) * 8);
    }
    int bR[4], bC[4], bS[4];
    #pragma unroll
    for (int i=0;i<4;i++){
        int s = (w*4 + i)*64 + lane;        // 0..1023
        int r = s >> 3, cs = s & 7;
        bS[i] = s; bR[i] = r; bC[i] = ((cs ^ (r & 7)) * 8);
    }

    #define PISSUE(ksv, buf) do {                                              \
        const int kb = (ksv)*64;                                               \
        _Pragma("unroll")                                                      \
        for (int i=0;i<2;i++)                                                  \
            gload_lds16(A  + (size_t)(m0 + aR[i])*D_ + kb + aC[i],             \
                        (unsigned short*)As + (buf)*4096 + aS[i]*8);           \
        _Pragma("unroll")                                                      \
        for (int i=0;i<4;i++)                                                  \
            gload_lds16(Bm + (size_t)(n0 + bR[i])*D_ + kb + bC[i],             \
                        (unsigned short*)Bs + (buf)*8192 + bS[i]*8);           \
    } while(0)

    for (int j = 0; j < 3; ++j){
        const int tid = xcd*192 + slot + j*64;
        const int zm  = tid >> 3, nn = tid & 7;
        const int which = zm >> 6, tm = zm & 63;
        const int m0 = tm * 64;
        const int n0 = nn * 128;

        const unsigned short* A  = which==0 ? A0 : (which==1 ? A1 : A2);
        const unsigned short* Bm = WtBase + ((size_t)which << 20);
        const float* bias        = which==0 ? b0 : (which==1 ? b1 : b2);
        unsigned short* Out      = OutBase + ((size_t)which << 22);
        const float oscale = (which==0) ? 0.04508422f : 1.0f;   // log2e/32

        float biasv[2];
        #pragma unroll
        for (int nt=0; nt<2; nt++)
            biasv[nt] = bias[n0 + w*32 + nt*16 + l15];

        f32x4 acc[4][2];
        #pragma unroll
        for (int i=0;i<4;i++)
            #pragma unroll
            for (int jj=0;jj<2;jj++) acc[i][jj] = (f32x4){0.f,0.f,0.f,0.f};

        PISSUE(0, 0);
        int cur = 0;
        for (int ks = 0; ks < 16; ++ks) {
            if (ks < 15) {
                PISSUE(ks+1, cur^1);                          // 6 loads in flight
                asm volatile("s_waitcnt vmcnt(6)" ::: "memory");
            } else {
                asm volatile("s_waitcnt vmcnt(0)" ::: "memory");
            }
            __builtin_amdgcn_s_barrier();
            __builtin_amdgcn_sched_barrier(0);

            const unsigned short* Asb = As + cur*4096;
            const unsigned short* Bsb = Bs + cur*8192;
            #pragma unroll
            for (int kh=0; kh<2; kh++){
                short8 aF[4], bF[2];
                #pragma unroll
                for (int mt=0; mt<4; mt++){
                    int r  = mt*16 + l15;
                    int cs = (kh*4 + quad) ^ (r & 7);
                    aF[mt] = *(const short8*)(Asb + r*64 + cs*8);
                }
                #pragma unroll
                for (int nt=0; nt<2; nt++){
                    int r  = w*32 + nt*16 + l15;
                    int cs = (kh*4 + quad) ^ (r & 7);
                    bF[nt] = *(const short8*)(Bsb + r*64 + cs*8);
                }
                #pragma unroll
                for (int mt=0; mt<4; mt++)
                    #pragma unroll
                    for (int nt=0; nt<2; nt++)
                        acc[mt][nt] = MFMA16(aF[mt], bF[nt], acc[mt][nt]);
            }
            __builtin_amdgcn_s_barrier();   // readers of cur done before overwrite
            cur ^= 1;
        }

        if (which != 2) {
            #pragma unroll
            for (int nt=0; nt<2; nt++){
                int n  = n0 + w*32 + nt*16 + l15;
                int hh = n >> 6, dh = n & 63;
                #pragma unroll
                for (int mt=0; mt<4; mt++){
                    #pragma unroll
                    for (int r=0; r<4; r++){
                        int m  = m0 + mt*16 + quad*4 + r;
                        int bb = m >> 11, ss = m & (S_-1);
                        float v = (acc[mt][nt][r] + biasv[nt]) * oscale;
                        Out[((size_t)((bb*H_ + hh)*S_ + ss))*DH_ + dh] = f2bf(v);
                    }
                }
            }
        } else {
            #pragma unroll
            for (int nt=0; nt<2; nt++){
                int n  = n0 + w*32 + nt*16 + l15;
                int hh = n >> 6, dh = n & 63;
                #pragma unroll
                for (int mt=0; mt<4; mt++){
                    int m  = m0 + mt*16 + quad*4;
                    int bb = m >> 11, ss = m & (S_-1);
                    uint2 pk;
                    pk.x = packp(acc[mt][nt][0] + biasv[nt], acc[mt][nt][1] + biasv[nt]);
                    pk.y = packp(acc[mt][nt][2] + biasv[nt], acc[mt][nt][3] + biasv[nt]);
                    *(uint2*)&Out[((size_t)((bb*H_ + hh)*DH_ + dh))*S_ + ss] = pk;
                }
            }
        }
    }
    #undef PISSUE
}

// ---------------------------------------------------------------------------
// Flash attention (unchanged from R10): fixed-max exp2 softmax, in-register P.
// Block = 256 q of one (b,h); 8 waves x 32 q (qs=2); both 64-key sub-tiles
// per wave (odd waves in (1,0) order). Grid (8,16,2) = 1 block/CU.
// ---------------------------------------------------------------------------
__global__ __launch_bounds__(512, 2) void attn_kernel(
    const unsigned short* __restrict__ ws, const int* __restrict__ mask,
    float* __restrict__ out)
{
    const unsigned short* Qh = ws;                      // [B][H][S][64], exp2-scaled
    const unsigned short* Kh = ws + (size_t)M_*D_;      // [B][H][S][64]
    const unsigned short* Vg = ws + 2*(size_t)M_*D_;    // [B][H][64][S]

    const int lin = blockIdx.x + (blockIdx.y << 3) + (blockIdx.z << 7);
    const int Wn  = (lin & 7)*32 + (lin >> 3);
    const int qt = Wn & 7;
    const int h  = (Wn >> 3) & 15;
    const int bb = Wn >> 7;

    const size_t base = ((size_t)(bb*H_ + h)) * S_ * DH_;
    const int q0 = qt * 256;

    __shared__ __align__(16) unsigned char smem[73728];
    unsigned short* KsB = (unsigned short*)smem;            // [2][128][64] key-permuted
    unsigned short* VtB = (unsigned short*)(smem + 32768);  // [2][128][64] true-key order
    float*          MsT = (float*)(smem + 65536);           // [2048] static mask bias
    float*          Ob  = (float*)smem;                     // [256][68] f32 alias (epi)

    const int t    = threadIdx.x;    // 0..511
    const int w    = t >> 6;         // 0..7 -> q rows w*32..w*32+31
    const int lane = t & 63;
    const int l15  = lane & 15;
    const int quad = lane >> 4;

    short8 qf[2][2];
    #pragma unroll
    for (int qs=0; qs<2; qs++){
        const unsigned short* qp = Qh + base + (size_t)(q0 + w*32 + qs*16 + l15)*DH_ + quad*8;
        qf[qs][0] = *(const short8*)(qp);
        qf[qs][1] = *(const short8*)(qp + 32);
    }

    f32x4 accO[2][4];
    #pragma unroll
    for (int qs=0; qs<2; qs++)
        #pragma unroll
        for (int i=0;i<4;i++) accO[qs][i] = (f32x4){0.f,0.f,0.f,0.f};
    f32x4 lv[2] = {(f32x4){0.f,0.f,0.f,0.f}, (f32x4){0.f,0.f,0.f,0.f}};

    int rr[2], cc[2], ssl[2], gK[2];
    #pragma unroll
    for (int i=0;i<2;i++){
        int s  = (w*2 + i)*64 + lane;   // 0..1023
        int r  = s >> 3, cs = s & 7;
        int r6 = r & 63;
        ssl[i] = s;
        rr[i]  = r;
        cc[i]  = (cs ^ (r & 7)) * 8;
        gK[i]  = (r & 64) + ((r6 >> 4) & 1)*32 + ((r6 >> 2) & 3)*8 + (r6 >> 5)*4 + (r6 & 3);
    }

    #define ISSUE128(k0v, p) do {                                              \
        _Pragma("unroll")                                                      \
        for (int i=0;i<2;i++){                                                 \
            gload_lds16(Kh + base + (size_t)((k0v) + gK[i])*DH_ + cc[i],       \
                        KsB + (p)*8192 + ssl[i]*8);                            \
            gload_lds16(Vg + base + (size_t)(rr[i] & 63)*S_ + (k0v)            \
                            + (rr[i] & 64) + cc[i],                            \
                        VtB + (p)*8192 + ssl[i]*8);                            \
        }                                                                      \
    } while(0)

    ISSUE128(0, 0);
    #pragma unroll
    for (int i=0;i<4;i++){
        int idx = i*512 + t;
        MsT[idx] = mask[bb*S_ + idx] ? 0.f : -1e9f;
    }
    __syncthreads();

    for (int it = 0; it < 16; ++it){
        const int p = it & 1;
        if (it < 15) ISSUE128((it+1)*128, 1-p);

        #pragma unroll
        for (int sbi = 0; sbi < 2; ++sbi){
            const int sb = sbi ^ (w & 1);    // de-phase the 2 waves per SIMD
            const unsigned short* Ks  = KsB + p*8192 + sb*4096;
            const unsigned short* Vts = VtB + p*8192 + sb*4096;
            const float*          Mp  = MsT + it*128 + sb*64;

            f32x4 msv[4];
            #pragma unroll
            for (int st=0; st<4; st++)
                msv[st] = *(const f32x4*)&Mp[(st&1)*32 + (st>>1)*4 + quad*8];

            short8 ka[4], kb[4];
            #pragma unroll
            for (int st=0; st<4; st++){
                int row = st*16 + l15;
                const unsigned short* kr = Ks + row*64;
                ka[st] = *(const short8*)(kr + ((quad    ) ^ (row & 7))*8);
                kb[st] = *(const short8*)(kr + ((quad + 4) ^ (row & 7))*8);
            }
            short8 vf[4][2];
            #pragma unroll
            for (int mt=0; mt<4; mt++){
                int row = mt*16 + l15;
                const unsigned short* vr = Vts + row*64;
                vf[mt][0] = *(const short8*)(vr + ((quad    ) ^ (row & 7))*8);
                vf[mt][1] = *(const short8*)(vr + ((quad + 4) ^ (row & 7))*8);
            }

            #pragma unroll
            for (int qs=0; qs<2; qs++){
                f32x4 sc[4];
                __builtin_amdgcn_s_setprio(1);
                #pragma unroll
                for (int st=0; st<4; st++){
                    f32x4 a = msv[st];
                    a = MFMA16(ka[st], qf[qs][0], a);
                    a = MFMA16(kb[st], qf[qs][1], a);
                    sc[st] = a;
                }
                __builtin_amdgcn_s_setprio(0);
                f32x4 pvv[4];
                #pragma unroll
                for (int st=0; st<4; st++)
                    #pragma unroll
                    for (int rj=0; rj<4; rj++)
                        pvv[st][rj] = __builtin_amdgcn_exp2f(sc[st][rj]);
                f32x4 s01 = pvv[0] + pvv[1];
                f32x4 s23 = pvv[2] + pvv[3];
                lv[qs] += (s01 + s23);
                u32x4 u0 = { cvtpk(pvv[0][0],pvv[0][1]), cvtpk(pvv[0][2],pvv[0][3]),
                             cvtpk(pvv[2][0],pvv[2][1]), cvtpk(pvv[2][2],pvv[2][3]) };
                u32x4 u1 = { cvtpk(pvv[1][0],pvv[1][1]), cvtpk(pvv[1][2],pvv[1][3]),
                             cvtpk(pvv[3][0],pvv[3][1]), cvtpk(pvv[3][2],pvv[3][3]) };
                short8 pf0 = __builtin_bit_cast(short8, u0);
                short8 pf1 = __builtin_bit_cast(short8, u1);
                __builtin_amdgcn_s_setprio(1);
                #pragma unroll
                for (int mt=0; mt<4; mt++){
                    accO[qs][mt] = MFMA16(vf[mt][0], pf0, accO[qs][mt]);
                    accO[qs][mt] = MFMA16(vf[mt][1], pf1, accO[qs][mt]);
                }
                __builtin_amdgcn_s_setprio(0);
            }
        }
        __syncthreads();
    }

    #pragma unroll
    for (int qs=0; qs<2; qs++){
        float l = (lv[qs][0] + lv[qs][1]) + (lv[qs][2] + lv[qs][3]);
        l += __shfl_xor(l, 16);
        l += __shfl_xor(l, 32);
        float invl = 1.0f / fmaxf(l, 1e-30f);
        #pragma unroll
        for (int mt=0; mt<4; mt++)
            #pragma unroll
            for (int r=0; r<4; r++)
                Ob[(w*32 + qs*16 + l15)*68 + mt*16 + quad*4 + r] = accO[qs][mt][r]*invl;
    }
    __syncthreads();

    #pragma unroll
    for (int i=0;i<8;i++){
        int f  = (i*512 + t)*4;
        int qq = f >> 6, dh = f & 63;
        float4 o = *(float4*)&Ob[qq*68 + dh];
        *(float4*)&out[((size_t)(bb*S_ + q0 + qq))*D_ + h*DH_ + dh] = o;
    }
    #undef ISSUE128
}

extern "C" void kernel_launch(void* const* d_in, const int* in_sizes, int n_in,
                              void* d_out, int out_size, void* d_ws, size_t ws_size,
                              hipStream_t stream) {
    const float* q    = (const float*)d_in[0];
    const float* k    = (const float*)d_in[1];
    const float* v    = (const float*)d_in[2];
    const int*   mask = (const int*)d_in[3];
    const float* Wq   = (const float*)d_in[4];
    const float* b0   = (const float*)d_in[5];
    const float* Wk   = (const float*)d_in[6];
    const float* b1   = (const float*)d_in[7];
    const float* Wv   = (const float*)d_in[8];
    const float* b2   = (const float*)d_in[9];
    float* out = (float*)d_out;
    unsigned short* ws = (unsigned short*)d_ws;   // 39.85 MB used

    // Xb slots: q -> ws; k,v -> d_out (scratch until attn overwrites it last)
    unsigned short* xq = ws + XB_OFF;
    unsigned short* xk = (unsigned short*)d_out;
    unsigned short* xv = (unsigned short*)d_out + 4194304;

    convert_all<<<dim3(2304,1,3), 256, 0, stream>>>(q, k, v, Wq, Wk, Wv,
                                                    xq, xk, xv, ws + WT_OFF);
    proj_gemm<<<dim3(512,1,1), 256, 0, stream>>>(xq, xk, xv, ws + WT_OFF,
                                                 b0, b1, b2, ws);
    attn_kernel<<<dim3(8,16,2), 512, 0, stream>>>(ws, mask, out);
}